// Round 1
// baseline (18.713 us; speedup 1.0000x reference)
//
#include <hip/hip_runtime.h>

#define BB 8
#define NN 4096
#define KK 2048
#define CC 256

__global__ __launch_bounds__(1024) void topk_scan_kernel(const int* __restrict__ idx,
                                                         int* __restrict__ rank) {
    const int b = blockIdx.x;
    const int t = threadIdx.x;                  // 0..1023, each handles 4 idx values
    const int4* idx4 = (const int4*)(idx + (size_t)b * NN);
    int4 v = idx4[t];
    int s = v.x + v.y + v.z + v.w;

    // inclusive scan of per-thread sums within the 64-lane wave
    const int lane = t & 63;
    int incl = s;
#pragma unroll
    for (int off = 1; off < 64; off <<= 1) {
        int up = __shfl_up(incl, off, 64);
        if (lane >= off) incl += up;
    }

    __shared__ int waveTot[16];
    const int wave = t >> 6;                    // 16 waves
    if (lane == 63) waveTot[wave] = incl;
    __syncthreads();

    int wo = 0;
    for (int w = 0; w < wave; ++w) wo += waveTot[w];

    const int base = wo + (incl - s);           // exclusive prefix for this thread's 1st elem
    int4 r;
    r.x = base;
    r.y = base + v.x;
    r.z = r.y + v.y;
    r.w = r.z + v.z;
    ((int4*)(rank + (size_t)b * NN))[t] = r;
}

__global__ __launch_bounds__(256) void topk_scatter_kernel(const float4* __restrict__ x,
                                                           const int* __restrict__ idx,
                                                           const int* __restrict__ rank,
                                                           float4* __restrict__ out) {
    const int C4 = CC / 4;                      // 64 float4 per row
    const long long row = (long long)blockIdx.x * 4 + (threadIdx.x >> 6);
    const int lane = threadIdx.x & 63;
    const int b = (int)(row >> 12);             // N = 4096 rows per batch

    float4 val = make_float4(0.f, 0.f, 0.f, 0.f);
    if (idx[row] > 0) {
        const int r = rank[row];
        val = x[((long long)b * KK + r) * C4 + lane];
    }
    out[row * C4 + lane] = val;
}

extern "C" void kernel_launch(void* const* d_in, const int* in_sizes, int n_in,
                              void* d_out, int out_size, void* d_ws, size_t ws_size,
                              hipStream_t stream) {
    const float* x  = (const float*)d_in[0];    // (B, K, C) float32
    const int* idx  = (const int*)d_in[1];      // (B, N) int32
    // d_in[2] = A (B, N, N) — only its shape matters; never read.
    float* out = (float*)d_out;                  // (B, N, C) float32
    int* rank = (int*)d_ws;                      // B*N ints = 128 KB scratch

    topk_scan_kernel<<<BB, 1024, 0, stream>>>(idx, rank);
    topk_scatter_kernel<<<(BB * NN) / 4, 256, 0, stream>>>(
        (const float4*)x, idx, rank, (float4*)out);
}

// Round 2
// 15.433 us; speedup vs baseline: 1.2126x; 1.2126x over previous
//
#include <hip/hip_runtime.h>

#define BB 8
#define NN 4096
#define KK 2048
#define CC 256

// One block = 256 threads = 4 waves; each wave copies/zeros one output row
// (64 lanes x float4 = 1024 B). The block computes its own rank base by
// reduce-summing idx[b, 0:rowStart) -- L2-resident after first touch, so no
// separate scan kernel / launch is needed.
__global__ __launch_bounds__(256) void topk_fused_kernel(const float4* __restrict__ x,
                                                         const int* __restrict__ idx,
                                                         float4* __restrict__ out) {
    const int bi = blockIdx.x;                 // 0..8191
    const int b = bi >> 10;                    // 1024 blocks per batch
    const int rowStart = (bi & 1023) * 4;      // first row (within batch) of this block
    const int t = threadIdx.x;
    const int lane = t & 63;
    const int wave = t >> 6;                   // 0..3

    const int* idxB = idx + (size_t)b * NN;
    const int4* idxB4 = (const int4*)idxB;

    // ---- reduce: sum of idx[0:rowStart) ----
    int partial = 0;
    const int n4 = rowStart >> 2;              // int4 count (rowStart % 4 == 0)
    for (int i = t; i < n4; i += 256) {
        int4 v = idxB4[i];
        partial += v.x + v.y + v.z + v.w;
    }
#pragma unroll
    for (int off = 32; off > 0; off >>= 1)
        partial += __shfl_down(partial, off, 64);

    __shared__ int waveSum[4];
    if (lane == 0) waveSum[wave] = partial;
    __syncthreads();
    const int base = waveSum[0] + waveSum[1] + waveSum[2] + waveSum[3];

    // ---- this block's 4 idx values (one broadcast int4) ----
    const int4 v4 = idxB4[rowStart >> 2];
    const int myIdx = (wave == 0) ? v4.x : (wave == 1) ? v4.y : (wave == 2) ? v4.z : v4.w;
    const int pre = ((wave > 0) ? v4.x : 0) + ((wave > 1) ? v4.y : 0) + ((wave > 2) ? v4.z : 0);

    // ---- copy or zero one row ----
    const long long row = (long long)b * NN + rowStart + wave;
    float4 val = make_float4(0.f, 0.f, 0.f, 0.f);
    if (myIdx > 0) {
        const int r = base + pre;              // rank of this row among selected
        val = x[((long long)b * KK + r) * (CC / 4) + lane];
    }
    out[row * (CC / 4) + lane] = val;
}

extern "C" void kernel_launch(void* const* d_in, const int* in_sizes, int n_in,
                              void* d_out, int out_size, void* d_ws, size_t ws_size,
                              hipStream_t stream) {
    const float* x  = (const float*)d_in[0];   // (B, K, C) float32
    const int* idx  = (const int*)d_in[1];     // (B, N) int32
    // d_in[2] = A (B, N, N) -- only its shape matters; never read.
    float* out = (float*)d_out;                // (B, N, C) float32

    topk_fused_kernel<<<(BB * NN) / 4, 256, 0, stream>>>(
        (const float4*)x, idx, (float4*)out);
}